// Round 16
// baseline (78.519 us; speedup 1.0000x reference)
//
#include <hip/hip_runtime.h>
#include <hip/hip_bf16.h>

typedef __attribute__((ext_vector_type(8))) short short8;
typedef __attribute__((ext_vector_type(4))) float f32x4;
typedef __attribute__((address_space(1))) const unsigned int as1_u32;
typedef __attribute__((address_space(3))) unsigned int as3_u32;

#define BM 128
#define BN 128
#define BK 32
#define NKT 16   // 512 / BK

static __device__ __forceinline__ unsigned short f2bf(float f) {
    union { __hip_bfloat16 h; unsigned short u; } cv;
    cv.h = __float2bfloat16(f);
    return cv.u;
}

__device__ __forceinline__ void gload16(const void* g, void* l) {
    __builtin_amdgcn_global_load_lds((as1_u32*)g, (as3_u32*)l, 16, 0, 0);
}

// Build WbigS: octonion-folded weight, bf16, PRE-SWIZZLED for the gload stream.
// Logical Wbig[m][kk] = sum_i C[i,j,k]*W[i,o,f]  (m=o*8+k col, kk=f*8+j K-dim).
// Chunk (nt=m>>7, H=kk>>5) = 128 cols x 32 K = 4096 elems, gloaded linearly.
// Within chunk: col c=m&127 holds its 32 K as 4 granules of 8; logical granule
// q=( (kk&31)>>3 ) stored at q^(c&3):  idx = (nt*16+H)*4096 + c*32 + (q^(c&3))*8 + (kk&7)
__global__ __launch_bounds__(256) void build_wbig(const float* __restrict__ W,
                                                  unsigned short* __restrict__ WbigS) {
    __shared__ float C[8][8][8];
    const int t = threadIdx.x;
    for (int i = t; i < 512; i += 256) ((float*)C)[i] = 0.0f;
    __syncthreads();
    if (t == 0) {
        C[0][0][0] = 1.0f;
        for (int i = 1; i < 8; ++i) { C[0][i][i] = 1.0f; C[i][0][i] = 1.0f; C[i][i][0] = -1.0f; }
        const int tr[7][3] = {{1,2,3},{1,4,5},{1,7,6},{2,4,6},{2,5,7},{3,4,7},{3,6,5}};
        for (int q = 0; q < 7; ++q) {
            const int a = tr[q][0], b = tr[q][1], c = tr[q][2];
            const int p[3][3] = {{a,b,c},{b,c,a},{c,a,b}};
            for (int u = 0; u < 3; ++u) {
                C[p[u][0]][p[u][1]][p[u][2]] = 1.0f;
                C[p[u][1]][p[u][0]][p[u][2]] = -1.0f;
            }
        }
    }
    __syncthreads();
    const int e = blockIdx.x * 256 + t;     // 0..262143
    const int m = e >> 9, kk = e & 511;
    const int o = m >> 3, k = m & 7, f = kk >> 3, j = kk & 7;
    float s = 0.0f;
#pragma unroll
    for (int i = 0; i < 8; ++i) s += C[i][j][k] * W[i * 4096 + o * 64 + f];

    const int nt = m >> 7, c = m & 127;
    const int H = kk >> 5, q = (kk >> 3) & 3, e8 = kk & 7;
    WbigS[((nt * 16 + H) * 4096) + c * 32 + ((q ^ (c & 3)) * 8) + e8] = f2bf(s);
}

// Out[65536][512] = X(fp32->bf16 at frag read) * Wbig^T + bias.
// m97-faithful: 128x128 tile, BK=32, 256 thr (4 waves, 64x64 wave-tiles).
// BOTH operands via global_load_lds (0 staging regs); A raw fp32 (cvt at read);
// source-address XOR swizzles -> ~2-way LDS reads. LDS 48 KB => 3 blocks/CU
// (12 waves/CU) -- TLP hides the syncthreads vmcnt drain (m114). NO manual
// scheduling: plain __syncthreads, compiler-ordered (m141 lesson).
__global__ __launch_bounds__(256, 3) void oct_gemm(const float* __restrict__ X,
                                                   const unsigned short* __restrict__ WbigS,
                                                   const float* __restrict__ Bias,
                                                   float* __restrict__ Out) {
    __shared__ float          Ah[2][4096];   // 2 x 16 KB: [128 rows][32 K] swizzled fp32
    __shared__ unsigned short Bh[2][4096];   // 2 x  8 KB: [128 cols][32 K] swizzled bf16

    // XCD swizzle: the 4 col-tiles of each row-tile land on one XCD (share A in L2).
    const int bid = blockIdx.x;          // 0..2047
    const int xcd = bid & 7;
    const int ix  = bid >> 3;            // 0..255
    const int mtile = xcd * 64 + (ix >> 2);
    const int nt    = ix & 3;
    const int rowBase = mtile * BM;
    const int colBase = nt * BN;

    const int t    = threadIdx.x;        // 0..255
    const int lane = t & 63;
    const int w    = t >> 6;             // 0..3
    const int wr   = w >> 1;             // 0..1 (64-row half)
    const int wc   = w & 1;              // 0..1 (64-col half)
    const int l15  = lane & 15;
    const int l4   = lane >> 4;          // 0..3

    // ---- A per-lane swizzled global sources (4 issues of 256 thr x 16 B) ----
    // slot s = (is*4+w)*64+lane: r=s>>3, j=s&7; holds logical fp32 col
    //   ((j>>1)^(r&3))*8 + ((j&1)^((r>>2)&1))*4   (XOR involution)
    const float* Asrc[4];
#pragma unroll
    for (int is = 0; is < 4; ++is) {
        const int s = (is * 4 + w) * 64 + lane;
        const int r = s >> 3, j = s & 7;
        const int c = (((j >> 1) ^ (r & 3)) << 3) + (((j & 1) ^ ((r >> 2) & 1)) << 2);
        Asrc[is] = X + (size_t)(rowBase + r) * 512 + c;
    }
    // B source: swizzle baked into WbigS -> linear stream
    const unsigned short* Bsrc = WbigS + nt * (16 * 4096) + (size_t)w * 512 + lane * 8;

    // LDS dest uniform offsets (HW adds lane*16B)
    // A: slot elem = s*4 fp32 -> uniform (is*4+w)*256 ; B: s*8 u16 -> (is*4+w)*512
#define GLOAD(HB, H) do { _Pragma("unroll") \
    for (int is = 0; is < 4; ++is) \
        gload16(Asrc[is] + (H) * 32, &Ah[HB][(is * 4 + w) * 256]); \
    _Pragma("unroll") \
    for (int is = 0; is < 2; ++is) \
        gload16(Bsrc + (H) * 4096 + is * 2048, &Bh[HB][(is * 4 + w) * 512]); \
    } while (0)

    // Frag-read offsets (fp32 / u16 elems), swizzle applied:
    const int asub = (l15 >> 2) & 1;
    const int aoff = (wr * 64 + l15) * 32 + ((l4 ^ (l15 & 3)) << 3);   // + mi*512
    const int boff = (wc * 64 + l15) * 32 + ((l4 ^ (l15 & 3)) << 3);   // + ni*512

    // Bias folded into accumulator init (D col = lane&15 for all 4 regs).
    f32x4 acc[4][4];
#pragma unroll
    for (int ni = 0; ni < 4; ++ni) {
        const float bv = Bias[colBase + wc * 64 + ni * 16 + l15];
#pragma unroll
        for (int mi = 0; mi < 4; ++mi) acc[mi][ni] = (f32x4){bv, bv, bv, bv};
    }

    GLOAD(0, 0);
    __syncthreads();

#pragma unroll
    for (int kt = 0; kt < NKT; ++kt) {
        if (kt + 1 < NKT) GLOAD((kt + 1) & 1, kt + 1);   // next tile -> other buffer

        // compute on buffer kt&1 (compiler schedules freely)
        short8 bf[4];
#pragma unroll
        for (int ni = 0; ni < 4; ++ni)
            bf[ni] = *reinterpret_cast<const short8*>(&Bh[kt & 1][boff + ni * 512]);
#pragma unroll
        for (int mi = 0; mi < 4; ++mi) {
            const f32x4 lo = *reinterpret_cast<const f32x4*>(&Ah[kt & 1][aoff + mi * 512 + asub * 4]);
            const f32x4 hi = *reinterpret_cast<const f32x4*>(&Ah[kt & 1][aoff + mi * 512 + (asub ^ 1) * 4]);
            short8 af;
            af[0] = (short)f2bf(lo[0]); af[1] = (short)f2bf(lo[1]);
            af[2] = (short)f2bf(lo[2]); af[3] = (short)f2bf(lo[3]);
            af[4] = (short)f2bf(hi[0]); af[5] = (short)f2bf(hi[1]);
            af[6] = (short)f2bf(hi[2]); af[7] = (short)f2bf(hi[3]);
#pragma unroll
            for (int ni = 0; ni < 4; ++ni)
                acc[mi][ni] = __builtin_amdgcn_mfma_f32_16x16x32_bf16(af, bf[ni], acc[mi][ni], 0, 0, 0);
        }

        __syncthreads();   // drains vmcnt(0): next tile staged; reads of this buf done
    }

    // Epilogue: plain fp32 stores (verified clean 131 MB write pattern).
#pragma unroll
    for (int mi = 0; mi < 4; ++mi) {
        const int row0 = rowBase + wr * 64 + mi * 16 + l4 * 4;
#pragma unroll
        for (int ni = 0; ni < 4; ++ni) {
            const int col = colBase + wc * 64 + ni * 16 + l15;
#pragma unroll
            for (int r = 0; r < 4; ++r)
                Out[(size_t)(row0 + r) * 512 + col] = acc[mi][ni][r];
        }
    }
#undef GLOAD
}

extern "C" void kernel_launch(void* const* d_in, const int* in_sizes, int n_in,
                              void* d_out, int out_size, void* d_ws, size_t ws_size,
                              hipStream_t stream) {
    const float* x = (const float*)d_in[0];   // [65536][512]
    const float* W = (const float*)d_in[1];   // [8][64][64]
    const float* b = (const float*)d_in[2];   // [512]
    float* out = (float*)d_out;               // [65536][512]
    unsigned short* WbigS = (unsigned short*)d_ws;  // 512 KB pre-swizzled stream

    build_wbig<<<1024, 256, 0, stream>>>(W, WbigS);
    oct_gemm<<<2048, 256, 0, stream>>>(x, WbigS, b, out);
}